// Round 4
// baseline (110.557 us; speedup 1.0000x reference)
//
#include <hip/hip_runtime.h>
#include <hip/hip_bf16.h>
#include <cstdint>
#include <cmath>

// Shapes (hard-coded): B=4, S=4096, D=1024, DK=DV=128.
// ws layout: Qb[16384][128]bf16 @0 (4MB) | Kb @4MB | Vt[B][128][4096]bf16 @8MB
//            | Wtq bf16[128][1024] @12MB | Wtk | Wtv (ends 12.75MB)
//            | Po[nsplit][16384][128]f32 @13MB | ml[nsplit][16384][2]f32 after.

typedef __bf16 bf16x8 __attribute__((ext_vector_type(8)));
typedef float f32x4 __attribute__((ext_vector_type(4)));
typedef float f32x16 __attribute__((ext_vector_type(16)));

__device__ __forceinline__ unsigned short f2bf(float f) {
  unsigned u = __float_as_uint(f);
  u += 0x7fffu + ((u >> 16) & 1u);   // RNE
  return (unsigned short)(u >> 16);
}

__device__ __forceinline__ bf16x8 ld_frag(const char* p) {
  uint4 u = *reinterpret_cast<const uint4*>(p);
  return __builtin_bit_cast(bf16x8, u);
}

__device__ __forceinline__ unsigned cvtpk_bf16(float lo, float hi) {
  unsigned r;
  asm("v_cvt_pk_bf16_f32 %0, %1, %2" : "=v"(r) : "v"(lo), "v"(hi));
  return r;
}

__device__ __forceinline__ void pl32swap(unsigned &a, unsigned &b) {
  asm("v_permlane32_swap_b32 %0, %1" : "+v"(a), "+v"(b));
}

__device__ __forceinline__ bf16x8 mk_frag(unsigned w0, unsigned w1, unsigned w2, unsigned w3) {
  uint4 u{w0, w1, w2, w3};
  return __builtin_bit_cast(bf16x8, u);
}

// Q is pre-scaled by (1/sqrt(128)) * log2(e) so softmax uses exp2 directly.
#define QSCALE_LOG2E 0.12751744f

// ---------------- W transpose: [1024][128] f32 -> [128][1024] bf16 ----------
__global__ __launch_bounds__(256) void prep_wt_kernel(
    const float* __restrict__ W0, const float* __restrict__ W1, const float* __restrict__ W2,
    unsigned short* __restrict__ T0, unsigned short* __restrict__ T1,
    unsigned short* __restrict__ T2) {
  const int mode = blockIdx.z;
  const float* W = (mode == 0) ? W0 : (mode == 1) ? W1 : W2;
  unsigned short* Wt = (mode == 0) ? T0 : (mode == 1) ? T1 : T2;
  __shared__ float tile[64][65];
  int kt = blockIdx.x, nt = blockIdx.y;   // (16, 2)
  int tid = threadIdx.x;
  int c = tid & 63;
  int r0 = (tid >> 6) * 16;
#pragma unroll
  for (int i = 0; i < 16; ++i) {
    int r = r0 + i;
    tile[r][c] = W[(size_t)(kt * 64 + r) * 128 + nt * 64 + c];
  }
  __syncthreads();
#pragma unroll
  for (int i = 0; i < 16; ++i) {
    int n = r0 + i;
    Wt[(size_t)(nt * 64 + n) * 1024 + kt * 64 + c] = f2bf(tile[c][n]);
  }
}

// ---------------- projections: X[16384][1024]f32 @ Wt -> bf16 outputs -------
// 64x128 tile, BK=64, double-buffered LDS + register prefetch (2-phase).
__global__ __launch_bounds__(256, 4) void proj_kernel(
    const float* __restrict__ qx, const float* __restrict__ kx, const float* __restrict__ vx,
    const unsigned short* __restrict__ Wtq, const unsigned short* __restrict__ Wtk,
    const unsigned short* __restrict__ Wtv,
    const float* __restrict__ bq, const float* __restrict__ bk, const float* __restrict__ bv,
    unsigned short* __restrict__ Qb, unsigned short* __restrict__ Kb,
    unsigned short* __restrict__ Vtb) {
  const int mode = blockIdx.y;  // 0=Q 1=K 2=V
  const float* x = (mode == 0) ? qx : (mode == 1) ? kx : vx;
  const unsigned short* Wt = (mode == 0) ? Wtq : (mode == 1) ? Wtk : Wtv;
  const float* bias = (mode == 0) ? bq : (mode == 1) ? bk : bv;

  __shared__ char lds[49152];  // A: 2 x 8KB @0, W: 2 x 16KB @16384

  const int tid = threadIdx.x;
  const int lane = tid & 63, wid = tid >> 6;
  const int l15 = lane & 15, hi = lane >> 4;
  const int wm = wid >> 1, wn = wid & 1;
  const long row0 = (long)blockIdx.x * 64;

  // staging decomposition (constant per thread)
  const int arow = tid >> 2, ac16 = tid & 3;      // A: 64 rows x 4 chunks of 16 f32
  const int wrow = tid >> 1, wc32 = tid & 1;      // W: 128 rows x 2 chunks of 32 bf16
  const int aswz = (arow & 7) << 4;
  const int aoff0 = (arow * 128 + ac16 * 32) ^ aswz;
  const int aoff1 = (arow * 128 + ac16 * 32 + 16) ^ aswz;
  const int wswz = (wrow & 7) << 4;
  int woff[4];
#pragma unroll
  for (int i = 0; i < 4; ++i) woff[i] = (wrow * 128 + wc32 * 64 + i * 16) ^ wswz;

  const float* asrc0 = x + (row0 + arow) * 1024 + ac16 * 16;
  const unsigned short* wsrc0 = Wt + (size_t)wrow * 1024 + wc32 * 32;

  f32x4 acc[2][4];
#pragma unroll
  for (int i = 0; i < 2; ++i)
#pragma unroll
    for (int j = 0; j < 4; ++j) acc[i][j] = f32x4{0.f, 0.f, 0.f, 0.f};

  float4 apf[4];
  uint4 wpf[4];
  // prologue: load tile 0
#pragma unroll
  for (int i = 0; i < 4; ++i) apf[i] = *reinterpret_cast<const float4*>(asrc0 + i * 4);
#pragma unroll
  for (int i = 0; i < 4; ++i) wpf[i] = *reinterpret_cast<const uint4*>(wsrc0 + i * 8);
  {
    uint4 p0{cvtpk_bf16(apf[0].x, apf[0].y), cvtpk_bf16(apf[0].z, apf[0].w),
             cvtpk_bf16(apf[1].x, apf[1].y), cvtpk_bf16(apf[1].z, apf[1].w)};
    uint4 p1{cvtpk_bf16(apf[2].x, apf[2].y), cvtpk_bf16(apf[2].z, apf[2].w),
             cvtpk_bf16(apf[3].x, apf[3].y), cvtpk_bf16(apf[3].z, apf[3].w)};
    *reinterpret_cast<uint4*>(lds + aoff0) = p0;
    *reinterpret_cast<uint4*>(lds + aoff1) = p1;
#pragma unroll
    for (int i = 0; i < 4; ++i) *reinterpret_cast<uint4*>(lds + 16384 + woff[i]) = wpf[i];
  }
  __syncthreads();

  int cur = 0;
  for (int kt = 0; kt < 16; ++kt) {
    if (kt < 15) {
      const int k1 = (kt + 1) * 64;
#pragma unroll
      for (int i = 0; i < 4; ++i) apf[i] = *reinterpret_cast<const float4*>(asrc0 + k1 + i * 4);
#pragma unroll
      for (int i = 0; i < 4; ++i) wpf[i] = *reinterpret_cast<const uint4*>(wsrc0 + k1 + i * 8);
    }
    // compute on buf[cur]
    char* bufA = lds + cur * 8192;
    char* bufW = lds + 16384 + cur * 16384;
#pragma unroll
    for (int kk = 0; kk < 2; ++kk) {
      bf16x8 af[2], wf[4];
#pragma unroll
      for (int mi = 0; mi < 2; ++mi) {
        int row = wm * 32 + mi * 16 + l15;
        af[mi] = ld_frag(bufA + ((row * 128 + kk * 64 + hi * 16) ^ ((row & 7) << 4)));
      }
#pragma unroll
      for (int ni = 0; ni < 4; ++ni) {
        int row = wn * 64 + ni * 16 + l15;
        wf[ni] = ld_frag(bufW + ((row * 128 + kk * 64 + hi * 16) ^ ((row & 7) << 4)));
      }
#pragma unroll
      for (int mi = 0; mi < 2; ++mi)
#pragma unroll
        for (int ni = 0; ni < 4; ++ni)
          acc[mi][ni] = __builtin_amdgcn_mfma_f32_16x16x32_bf16(af[mi], wf[ni], acc[mi][ni], 0, 0, 0);
    }
    if (kt < 15) {
      char* nA = lds + (cur ^ 1) * 8192;
      char* nW = lds + 16384 + (cur ^ 1) * 16384;
      uint4 p0{cvtpk_bf16(apf[0].x, apf[0].y), cvtpk_bf16(apf[0].z, apf[0].w),
               cvtpk_bf16(apf[1].x, apf[1].y), cvtpk_bf16(apf[1].z, apf[1].w)};
      uint4 p1{cvtpk_bf16(apf[2].x, apf[2].y), cvtpk_bf16(apf[2].z, apf[2].w),
               cvtpk_bf16(apf[3].x, apf[3].y), cvtpk_bf16(apf[3].z, apf[3].w)};
      *reinterpret_cast<uint4*>(nA + aoff0) = p0;
      *reinterpret_cast<uint4*>(nA + aoff1) = p1;
#pragma unroll
      for (int i = 0; i < 4; ++i) *reinterpret_cast<uint4*>(nW + woff[i]) = wpf[i];
      __syncthreads();
      cur ^= 1;
    }
  }

  // epilogue: +bias, (Q: * scale), store
#pragma unroll
  for (int ni = 0; ni < 4; ++ni) {
    int n = wn * 64 + ni * 16 + l15;
    float bv_ = bias[n];
#pragma unroll
    for (int mi = 0; mi < 2; ++mi) {
      long m = row0 + wm * 32 + mi * 16 + hi * 4;
      f32x4 a = acc[mi][ni];
      if (mode == 2) {
        int bb = (int)(m >> 12);
        int s = (int)(m & 4095);
        ushort4 pk;
        pk.x = f2bf(a.x + bv_); pk.y = f2bf(a.y + bv_);
        pk.z = f2bf(a.z + bv_); pk.w = f2bf(a.w + bv_);
        *reinterpret_cast<ushort4*>(Vtb + ((size_t)(bb * 128 + n)) * 4096 + s) = pk;
      } else {
        const float sc = (mode == 0) ? QSCALE_LOG2E : 1.0f;
        unsigned short* outp = (mode == 0) ? Qb : Kb;
        outp[(m + 0) * 128 + n] = f2bf((a.x + bv_) * sc);
        outp[(m + 1) * 128 + n] = f2bf((a.y + bv_) * sc);
        outp[(m + 2) * 128 + n] = f2bf((a.z + bv_) * sc);
        outp[(m + 3) * 128 + n] = f2bf((a.w + bv_) * sc);
      }
    }
  }
}

// ---------------- flash attention (32x32 swapped-operand, KV-split) ---------
__global__ __launch_bounds__(256, 2) void attn_kernel(
    const unsigned short* __restrict__ Qb, const unsigned short* __restrict__ Kb,
    const unsigned short* __restrict__ Vtb, float* __restrict__ Po,
    float* __restrict__ ml, int tps) {
  __shared__ uint4 ldsK4[1024];  // 64 kv-rows x 128 d bf16, swizzled (16KB)
  __shared__ uint4 ldsV4[1024];  // 128 dv-rows x 64 k bf16, swizzled (16KB)
  char* ldsK = (char*)ldsK4;
  char* ldsV = (char*)ldsV4;

  const int tid = threadIdx.x;
  const int lane = tid & 63, wid = tid >> 6;
  const int l31 = lane & 31, hi = lane >> 5;
  const int split = blockIdx.y;
  const int b = blockIdx.z;
  const int qbase = blockIdx.x * 128 + wid * 32;  // within batch
  const size_t growq = (size_t)b * 4096 + qbase + l31;

  // Q fragments (B-operand): qf[kt] elem e <-> d = kt*16 + hi*8 + e
  bf16x8 qf[8];
  {
    const unsigned short* qp = Qb + growq * 128 + hi * 8;
#pragma unroll
    for (int kt = 0; kt < 8; ++kt)
      qf[kt] = __builtin_bit_cast(bf16x8, *reinterpret_cast<const uint4*>(qp + kt * 16));
  }

  f32x16 oacc[4];
#pragma unroll
  for (int d = 0; d < 4; ++d)
#pragma unroll
    for (int j = 0; j < 16; ++j) oacc[d][j] = 0.f;
  float mrun = -INFINITY, lrun = 0.f;

  const int t0 = split * tps, t1 = t0 + tps;

  for (int t = t0; t < t1; ++t) {
    const int kv0 = t * 64;
    const char* kg = (const char*)Kb + ((size_t)(b * 4096) + kv0) * 256;
#pragma unroll
    for (int i = 0; i < 4; ++i) {
      int u = tid + 256 * i;
      int row = u >> 4, c = u & 15;
      uint4 val = *reinterpret_cast<const uint4*>(kg + row * 256 + c * 16);
      *reinterpret_cast<uint4*>(ldsK + ((row * 256 + c * 16) ^ ((row & 7) << 4))) = val;
    }
    const char* vg = (const char*)Vtb + (size_t)b * 128 * 4096 * 2 + (size_t)kv0 * 2;
#pragma unroll
    for (int i = 0; i < 4; ++i) {
      int u = tid + 256 * i;
      int dv = u >> 3, c = u & 7;
      uint4 val = *reinterpret_cast<const uint4*>(vg + (size_t)dv * 8192 + c * 16);
      *reinterpret_cast<uint4*>(ldsV + ((dv * 128 + c * 16) ^ ((dv & 7) << 4))) = val;
    }
    __syncthreads();

    // ---- QK^T (swapped): sc_c[reg] = S[kv = (reg&3)+8*(reg>>2)+4*hi + 32c][q = l31]
    f32x16 sc0, sc1;
#pragma unroll
    for (int j = 0; j < 16; ++j) { sc0[j] = 0.f; sc1[j] = 0.f; }
    __builtin_amdgcn_s_setprio(1);
#pragma unroll
    for (int kvb = 0; kvb < 2; ++kvb) {
      int row = kvb * 32 + l31;
      int rowoff = row * 256, swz = (row & 7) << 4;
#pragma unroll
      for (int kt = 0; kt < 8; ++kt) {
        bf16x8 kf = ld_frag(ldsK + ((rowoff + kt * 32 + hi * 16) ^ swz));
        if (kvb == 0) sc0 = __builtin_amdgcn_mfma_f32_32x32x16_bf16(kf, qf[kt], sc0, 0, 0, 0);
        else          sc1 = __builtin_amdgcn_mfma_f32_32x32x16_bf16(kf, qf[kt], sc1, 0, 0, 0);
      }
    }
    __builtin_amdgcn_s_setprio(0);

    // ---- online softmax, fully per-lane (q = l31)
    float tmx[16];
#pragma unroll
    for (int i = 0; i < 16; ++i) tmx[i] = fmaxf(sc0[i], sc1[i]);
#pragma unroll
    for (int s = 8; s > 0; s >>= 1)
#pragma unroll
      for (int i = 0; i < s; ++i) tmx[i] = fmaxf(tmx[i], tmx[i + s]);
    float mt = tmx[0];
    mt = fmaxf(mt, __shfl_xor(mt, 32));

    // defer-max (T13)
    if (!__all(mt - mrun <= 8.0f)) {
      float mnew = fmaxf(mrun, mt);
      float scl = exp2f(mrun - mnew);
      mrun = mnew;
      lrun *= scl;
#pragma unroll
      for (int d = 0; d < 4; ++d)
#pragma unroll
        for (int j = 0; j < 16; ++j) oacc[d][j] *= scl;
    }

    // P = exp2(S - m) in-register
#pragma unroll
    for (int i = 0; i < 16; ++i) {
      sc0[i] = exp2f(sc0[i] - mrun);
      sc1[i] = exp2f(sc1[i] - mrun);
    }
    float ts[16];
#pragma unroll
    for (int i = 0; i < 16; ++i) ts[i] = sc0[i] + sc1[i];
#pragma unroll
    for (int s = 8; s > 0; s >>= 1)
#pragma unroll
      for (int i = 0; i < s; ++i) ts[i] += ts[i + s];
    float psum = ts[0];
    psum += __shfl_xor(psum, 32);
    lrun += psum;

    // ---- P -> bf16 fragments via cvt_pk + permlane32_swap (T12)
    bf16x8 pa[4];
#pragma unroll
    for (int c = 0; c < 2; ++c) {
      const f32x16& p = c ? sc1 : sc0;
#pragma unroll
      for (int g = 0; g < 2; ++g) {
        const int base = g * 8;
        unsigned a0 = cvtpk_bf16(p[base + 0], p[base + 1]);
        unsigned b0 = cvtpk_bf16(p[base + 4], p[base + 5]);
        pl32swap(a0, b0);
        unsigned a1 = cvtpk_bf16(p[base + 2], p[base + 3]);
        unsigned b1 = cvtpk_bf16(p[base + 6], p[base + 7]);
        pl32swap(a1, b1);
        pa[c * 2 + g] = mk_frag(a0, a1, b0, b1);
      }
    }

    // ---- PV (swapped): oacc[dvb] += mfma(A=Vt rows, B=P^T)
    __builtin_amdgcn_s_setprio(1);
#pragma unroll
    for (int dvb = 0; dvb < 4; ++dvb) {
      int vrow = dvb * 32 + l31;
      int voff = vrow * 128, vswz = (vrow & 7) << 4;
#pragma unroll
      for (int tt = 0; tt < 4; ++tt) {
        bf16x8 vf = ld_frag(ldsV + ((voff + tt * 32 + hi * 16) ^ vswz));
        oacc[dvb] = __builtin_amdgcn_mfma_f32_32x32x16_bf16(vf, pa[tt], oacc[dvb], 0, 0, 0);
      }
    }
    __builtin_amdgcn_s_setprio(0);
    __syncthreads();
  }

  // ---- epilogue: ml + O^T -> O via per-wave LDS transpose, coalesced stores
  if (hi == 0) {
    float* mlp = ml + (size_t)split * 32768 + growq * 2;
    mlp[0] = mrun; mlp[1] = lrun;
  }

  float* po = Po + ((size_t)split << 21) + ((size_t)b * 4096 + qbase) * 128;
  char* tbase = ldsK + wid * 4096;  // 32q x 32dv f32 = 4KB per wave
  for (int dvb = 0; dvb < 4; ++dvb) {
#pragma unroll
    for (int g = 0; g < 4; ++g) {
      float4 w4{oacc[dvb][g * 4 + 0], oacc[dvb][g * 4 + 1],
                oacc[dvb][g * 4 + 2], oacc[dvb][g * 4 + 3]};
      int off = (l31 * 128 + g * 32 + hi * 16) ^ ((l31 & 7) << 4);
      *reinterpret_cast<float4*>(tbase + off) = w4;
    }
    asm volatile("s_waitcnt lgkmcnt(0)" ::: "memory");
    __builtin_amdgcn_sched_barrier(0);
#pragma unroll
    for (int qq = 0; qq < 4; ++qq) {
      int q = qq * 8 + (lane >> 3);
      int off = (q * 128 + (lane & 7) * 16) ^ ((q & 7) << 4);
      float4 r4 = *reinterpret_cast<const float4*>(tbase + off);
      *reinterpret_cast<float4*>(po + (size_t)q * 128 + dvb * 32 + (lane & 7) * 4) = r4;
    }
    asm volatile("s_waitcnt lgkmcnt(0)" ::: "memory");
    __builtin_amdgcn_sched_barrier(0);
  }
}

// ---------------- combine partials ------------------------------------------
template <int NS>
__global__ __launch_bounds__(256) void combine_kernel(const float* __restrict__ Po,
                                                      const float* __restrict__ ml,
                                                      float* __restrict__ out) {
  int idx = blockIdx.x * 256 + threadIdx.x;  // 16384*32 float4-units
  int grow = idx >> 5;
  int c4 = (idx & 31) * 4;
  float m[NS], l[NS];
  float M = -INFINITY;
#pragma unroll
  for (int s = 0; s < NS; ++s) {
    m[s] = ml[(size_t)s * 32768 + grow * 2 + 0];
    l[s] = ml[(size_t)s * 32768 + grow * 2 + 1];
    M = fmaxf(M, m[s]);
  }
  float L = 0.f, w[NS];
#pragma unroll
  for (int s = 0; s < NS; ++s) {
    w[s] = exp2f(m[s] - M);   // log2 domain
    L += l[s] * w[s];
  }
  float invL = 1.0f / L;
  float4 acc = {0.f, 0.f, 0.f, 0.f};
#pragma unroll
  for (int s = 0; s < NS; ++s) {
    float4 p = *reinterpret_cast<const float4*>(Po + ((size_t)s << 21) + (size_t)grow * 128 + c4);
    acc.x += p.x * w[s]; acc.y += p.y * w[s];
    acc.z += p.z * w[s]; acc.w += p.w * w[s];
  }
  acc.x *= invL; acc.y *= invL; acc.z *= invL; acc.w *= invL;
  *reinterpret_cast<float4*>(out + (size_t)grow * 128 + c4) = acc;
}

extern "C" void kernel_launch(void* const* d_in, const int* in_sizes, int n_in,
                              void* d_out, int out_size, void* d_ws, size_t ws_size,
                              hipStream_t stream) {
  const float* q  = (const float*)d_in[0];
  const float* k  = (const float*)d_in[1];
  const float* v  = (const float*)d_in[2];
  const float* Wq = (const float*)d_in[3];
  const float* bq = (const float*)d_in[4];
  const float* Wk = (const float*)d_in[5];
  const float* bk = (const float*)d_in[6];
  const float* Wv = (const float*)d_in[7];
  const float* bv = (const float*)d_in[8];
  float* out = (float*)d_out;

  char* ws = (char*)d_ws;
  unsigned short* Qb  = (unsigned short*)(ws);
  unsigned short* Kb  = (unsigned short*)(ws + (4u << 20));
  unsigned short* Vtb = (unsigned short*)(ws + (8u << 20));
  unsigned short* Wtq = (unsigned short*)(ws + (12u << 20));
  unsigned short* Wtk = (unsigned short*)(ws + (12u << 20) + (256u << 10));
  unsigned short* Wtv = (unsigned short*)(ws + (12u << 20) + (512u << 10));

  const size_t base = (size_t)13 << 20;
  const size_t per = ((size_t)8 << 20) + ((size_t)128 << 10);
  int nsplit = 1;
  if (ws_size >= base + 4 * per) nsplit = 4;
  else if (ws_size >= base + 2 * per) nsplit = 2;
  float* Po = (float*)(ws + base);
  float* ml = (float*)(ws + base + (size_t)nsplit * ((size_t)8 << 20));

  prep_wt_kernel<<<dim3(16, 2, 3), 256, 0, stream>>>(Wq, Wk, Wv, Wtq, Wtk, Wtv);
  proj_kernel<<<dim3(256, 3), 256, 0, stream>>>(q, k, v, Wtq, Wtk, Wtv, bq, bk, bv, Qb, Kb, Vtb);
  attn_kernel<<<dim3(32, nsplit, 4), 256, 0, stream>>>(Qb, Kb, Vtb, Po, ml, 64 / nsplit);
  if (nsplit == 4)      combine_kernel<4><<<2048, 256, 0, stream>>>(Po, ml, out);
  else if (nsplit == 2) combine_kernel<2><<<2048, 256, 0, stream>>>(Po, ml, out);
  else                  combine_kernel<1><<<2048, 256, 0, stream>>>(Po, ml, out);
}

// Round 5
// 107.383 us; speedup vs baseline: 1.0296x; 1.0296x over previous
//
#include <hip/hip_runtime.h>
#include <hip/hip_bf16.h>
#include <cstdint>
#include <cmath>

// Shapes (hard-coded): B=4, S=4096, D=1024, DK=DV=128.
// ws layout: Qb[16384][128]bf16 @0 (4MB) | Kb @4MB | Vt[B][128][4096]bf16 @8MB
//            | Wtq bf16[128][1024] @12MB | Wtk | Wtv (ends 12.75MB)
//            | Po[nsplit][16384][128]f32 @13MB | ml[nsplit][16384][2]f32 after.

typedef __bf16 bf16x8 __attribute__((ext_vector_type(8)));
typedef float f32x4 __attribute__((ext_vector_type(4)));
typedef float f32x16 __attribute__((ext_vector_type(16)));

typedef const __attribute__((address_space(1))) unsigned int* gp_t;
typedef __attribute__((address_space(3))) unsigned int* lp_t;

__device__ __forceinline__ unsigned short f2bf(float f) {
  unsigned u = __float_as_uint(f);
  u += 0x7fffu + ((u >> 16) & 1u);   // RNE
  return (unsigned short)(u >> 16);
}

__device__ __forceinline__ bf16x8 ld_frag(const char* p) {
  uint4 u = *reinterpret_cast<const uint4*>(p);
  return __builtin_bit_cast(bf16x8, u);
}

__device__ __forceinline__ unsigned cvtpk_bf16(float lo, float hi) {
  unsigned r;
  asm("v_cvt_pk_bf16_f32 %0, %1, %2" : "=v"(r) : "v"(lo), "v"(hi));
  return r;
}

__device__ __forceinline__ void pl32swap(unsigned &a, unsigned &b) {
  asm("v_permlane32_swap_b32 %0, %1" : "+v"(a), "+v"(b));
}

__device__ __forceinline__ bf16x8 mk_frag(unsigned w0, unsigned w1, unsigned w2, unsigned w3) {
  uint4 u{w0, w1, w2, w3};
  return __builtin_bit_cast(bf16x8, u);
}

// Q is pre-scaled by (1/sqrt(128)) * log2(e) so softmax uses exp2 directly.
#define QSCALE_LOG2E 0.12751744f

// ---------------- W transpose: [1024][128] f32 -> [128][1024] bf16 ----------
__global__ __launch_bounds__(256) void prep_wt_kernel(
    const float* __restrict__ W0, const float* __restrict__ W1, const float* __restrict__ W2,
    unsigned short* __restrict__ T0, unsigned short* __restrict__ T1,
    unsigned short* __restrict__ T2) {
  const int mode = blockIdx.z;
  const float* W = (mode == 0) ? W0 : (mode == 1) ? W1 : W2;
  unsigned short* Wt = (mode == 0) ? T0 : (mode == 1) ? T1 : T2;
  __shared__ float tile[64][65];
  int kt = blockIdx.x, nt = blockIdx.y;   // (16, 2)
  int tid = threadIdx.x;
  int c = tid & 63;
  int r0 = (tid >> 6) * 16;
#pragma unroll
  for (int i = 0; i < 16; ++i) {
    int r = r0 + i;
    tile[r][c] = W[(size_t)(kt * 64 + r) * 128 + nt * 64 + c];
  }
  __syncthreads();
#pragma unroll
  for (int i = 0; i < 16; ++i) {
    int n = r0 + i;
    Wt[(size_t)(nt * 64 + n) * 1024 + kt * 64 + c] = f2bf(tile[c][n]);
  }
}

// ---------------- projections: X[16384][1024]f32 @ Wt -> bf16 outputs -------
// 64x128 tile, BK=64, dbuf LDS. A: contiguous 16B/lane loads + cvt + ds_write.
// W: global_load_lds width-16, linear LDS dest + pre-swizzled global source.
__global__ __launch_bounds__(256, 4) void proj_kernel(
    const float* __restrict__ qx, const float* __restrict__ kx, const float* __restrict__ vx,
    const unsigned short* __restrict__ Wtq, const unsigned short* __restrict__ Wtk,
    const unsigned short* __restrict__ Wtv,
    const float* __restrict__ bq, const float* __restrict__ bk, const float* __restrict__ bv,
    unsigned short* __restrict__ Qb, unsigned short* __restrict__ Kb,
    unsigned short* __restrict__ Vtb) {
  const int mode = blockIdx.y;  // 0=Q 1=K 2=V
  const float* x = (mode == 0) ? qx : (mode == 1) ? kx : vx;
  const unsigned short* Wt = (mode == 0) ? Wtq : (mode == 1) ? Wtk : Wtv;
  const float* bias = (mode == 0) ? bq : (mode == 1) ? bk : bv;

  __shared__ char lds[49152];  // A dbuf: 2 x 8KB @0, W dbuf: 2 x 16KB @16384

  const int tid = threadIdx.x;
  const int lane = tid & 63, wid = tid >> 6;
  const int l15 = lane & 15, hi = lane >> 4;
  const int wm = wid >> 1, wn = wid & 1;
  const long row0 = (long)blockIdx.x * 64;

  // A staging: u = i*256 + tid; row = u>>4 (= arow + 16i), c = u&15.
  // 16 lanes x 16B = one contiguous 256B row K-slice per row (line-minimal).
  const int arow = tid >> 4, ac = tid & 15;
  const float* asrc = x + (row0 + arow) * 1024 + ac * 4;
  const int aoff = (arow * 128 + ac * 8) ^ ((arow & 7) << 4);   // + i*2048 per i

  // W staging: u = i*256 + tid; row = u>>3 (= (tid>>3) + 32i), c = u&7.
  // LDS dest linear (u*16); global source col pre-swizzled: c' = c ^ (row&7).
  const int wrow = tid >> 3;
  const int wcs = (tid & 7) ^ (wrow & 7);
  const char* wsrc = (const char*)Wt + (size_t)wrow * 2048 + wcs * 16;  // +i*65536 +kt*128

  f32x4 acc[2][4];
#pragma unroll
  for (int i = 0; i < 2; ++i)
#pragma unroll
    for (int j = 0; j < 4; ++j) acc[i][j] = f32x4{0.f, 0.f, 0.f, 0.f};

  float4 apf[4];

  // prologue: stage tile 0
#pragma unroll
  for (int i = 0; i < 4; ++i)
    apf[i] = *reinterpret_cast<const float4*>(asrc + i * 16384);
#pragma unroll
  for (int i = 0; i < 4; ++i)
    __builtin_amdgcn_global_load_lds((gp_t)(wsrc + i * 65536),
                                     (lp_t)(lds + 16384 + i * 4096 + wid * 1024), 16, 0, 0);
#pragma unroll
  for (int i = 0; i < 4; ++i) {
    uint2 w{cvtpk_bf16(apf[i].x, apf[i].y), cvtpk_bf16(apf[i].z, apf[i].w)};
    *reinterpret_cast<uint2*>(lds + aoff + i * 2048) = w;
  }
  __syncthreads();

  int cur = 0;
  for (int kt = 0; kt < 16; ++kt) {
    if (kt < 15) {
      const int kf = (kt + 1) * 64;   // f32 elements
#pragma unroll
      for (int i = 0; i < 4; ++i)
        apf[i] = *reinterpret_cast<const float4*>(asrc + i * 16384 + kf);
      char* nW = lds + 16384 + (cur ^ 1) * 16384;
#pragma unroll
      for (int i = 0; i < 4; ++i)
        __builtin_amdgcn_global_load_lds((gp_t)(wsrc + i * 65536 + (kt + 1) * 128),
                                         (lp_t)(nW + i * 4096 + wid * 1024), 16, 0, 0);
    }
    // compute on buf[cur]
    char* bufA = lds + cur * 8192;
    char* bufW = lds + 16384 + cur * 16384;
#pragma unroll
    for (int kk = 0; kk < 2; ++kk) {
      bf16x8 af[2], wf[4];
#pragma unroll
      for (int mi = 0; mi < 2; ++mi) {
        int row = wm * 32 + mi * 16 + l15;
        af[mi] = ld_frag(bufA + ((row * 128 + kk * 64 + hi * 16) ^ ((row & 7) << 4)));
      }
#pragma unroll
      for (int ni = 0; ni < 4; ++ni) {
        int row = wn * 64 + ni * 16 + l15;
        wf[ni] = ld_frag(bufW + ((row * 128 + kk * 64 + hi * 16) ^ ((row & 7) << 4)));
      }
#pragma unroll
      for (int mi = 0; mi < 2; ++mi)
#pragma unroll
        for (int ni = 0; ni < 4; ++ni)
          acc[mi][ni] = __builtin_amdgcn_mfma_f32_16x16x32_bf16(af[mi], wf[ni], acc[mi][ni], 0, 0, 0);
    }
    if (kt < 15) {
      char* nA = lds + (cur ^ 1) * 8192;
#pragma unroll
      for (int i = 0; i < 4; ++i) {
        uint2 w{cvtpk_bf16(apf[i].x, apf[i].y), cvtpk_bf16(apf[i].z, apf[i].w)};
        *reinterpret_cast<uint2*>(nA + aoff + i * 2048) = w;
      }
    }
    __syncthreads();
    cur ^= 1;
  }

  // epilogue: +bias, (Q: * scale), store
#pragma unroll
  for (int ni = 0; ni < 4; ++ni) {
    int n = wn * 64 + ni * 16 + l15;
    float bv_ = bias[n];
#pragma unroll
    for (int mi = 0; mi < 2; ++mi) {
      long m = row0 + wm * 32 + mi * 16 + hi * 4;
      f32x4 a = acc[mi][ni];
      if (mode == 2) {
        int bb = (int)(m >> 12);
        int s = (int)(m & 4095);
        ushort4 pk;
        pk.x = f2bf(a.x + bv_); pk.y = f2bf(a.y + bv_);
        pk.z = f2bf(a.z + bv_); pk.w = f2bf(a.w + bv_);
        *reinterpret_cast<ushort4*>(Vtb + ((size_t)(bb * 128 + n)) * 4096 + s) = pk;
      } else {
        const float sc = (mode == 0) ? QSCALE_LOG2E : 1.0f;
        unsigned short* outp = (mode == 0) ? Qb : Kb;
        outp[(m + 0) * 128 + n] = f2bf((a.x + bv_) * sc);
        outp[(m + 1) * 128 + n] = f2bf((a.y + bv_) * sc);
        outp[(m + 2) * 128 + n] = f2bf((a.z + bv_) * sc);
        outp[(m + 3) * 128 + n] = f2bf((a.w + bv_) * sc);
      }
    }
  }
}

// ---------------- flash attention (32x32 swapped-operand, KV-split) ---------
__global__ __launch_bounds__(256, 2) void attn_kernel(
    const unsigned short* __restrict__ Qb, const unsigned short* __restrict__ Kb,
    const unsigned short* __restrict__ Vtb, float* __restrict__ Po,
    float* __restrict__ ml, int tps) {
  __shared__ uint4 ldsK4[1024];  // 64 kv-rows x 128 d bf16, swizzled (16KB)
  __shared__ uint4 ldsV4[1024];  // 128 dv-rows x 64 k bf16, swizzled (16KB)
  char* ldsK = (char*)ldsK4;
  char* ldsV = (char*)ldsV4;

  const int tid = threadIdx.x;
  const int lane = tid & 63, wid = tid >> 6;
  const int l31 = lane & 31, hi = lane >> 5;
  const int split = blockIdx.y;
  const int b = blockIdx.z;
  const int qbase = blockIdx.x * 128 + wid * 32;  // within batch
  const size_t growq = (size_t)b * 4096 + qbase + l31;

  // Q fragments (B-operand): qf[kt] elem e <-> d = kt*16 + hi*8 + e
  bf16x8 qf[8];
  {
    const unsigned short* qp = Qb + growq * 128 + hi * 8;
#pragma unroll
    for (int kt = 0; kt < 8; ++kt)
      qf[kt] = __builtin_bit_cast(bf16x8, *reinterpret_cast<const uint4*>(qp + kt * 16));
  }

  f32x16 oacc[4];
#pragma unroll
  for (int d = 0; d < 4; ++d)
#pragma unroll
    for (int j = 0; j < 16; ++j) oacc[d][j] = 0.f;
  float mrun = -INFINITY, lrun = 0.f;

  const int t0 = split * tps, t1 = t0 + tps;

  for (int t = t0; t < t1; ++t) {
    const int kv0 = t * 64;
    const char* kg = (const char*)Kb + ((size_t)(b * 4096) + kv0) * 256;
#pragma unroll
    for (int i = 0; i < 4; ++i) {
      int u = tid + 256 * i;
      int row = u >> 4, c = u & 15;
      uint4 val = *reinterpret_cast<const uint4*>(kg + row * 256 + c * 16);
      *reinterpret_cast<uint4*>(ldsK + ((row * 256 + c * 16) ^ ((row & 7) << 4))) = val;
    }
    const char* vg = (const char*)Vtb + (size_t)b * 128 * 4096 * 2 + (size_t)kv0 * 2;
#pragma unroll
    for (int i = 0; i < 4; ++i) {
      int u = tid + 256 * i;
      int dv = u >> 3, c = u & 7;
      uint4 val = *reinterpret_cast<const uint4*>(vg + (size_t)dv * 8192 + c * 16);
      *reinterpret_cast<uint4*>(ldsV + ((dv * 128 + c * 16) ^ ((dv & 7) << 4))) = val;
    }
    __syncthreads();

    // ---- QK^T (swapped): sc_c[reg] = S[kv = (reg&3)+8*(reg>>2)+4*hi + 32c][q = l31]
    f32x16 sc0, sc1;
#pragma unroll
    for (int j = 0; j < 16; ++j) { sc0[j] = 0.f; sc1[j] = 0.f; }
    __builtin_amdgcn_s_setprio(1);
#pragma unroll
    for (int kvb = 0; kvb < 2; ++kvb) {
      int row = kvb * 32 + l31;
      int rowoff = row * 256, swz = (row & 7) << 4;
#pragma unroll
      for (int kt = 0; kt < 8; ++kt) {
        bf16x8 kf = ld_frag(ldsK + ((rowoff + kt * 32 + hi * 16) ^ swz));
        if (kvb == 0) sc0 = __builtin_amdgcn_mfma_f32_32x32x16_bf16(kf, qf[kt], sc0, 0, 0, 0);
        else          sc1 = __builtin_amdgcn_mfma_f32_32x32x16_bf16(kf, qf[kt], sc1, 0, 0, 0);
      }
    }
    __builtin_amdgcn_s_setprio(0);

    // ---- online softmax, fully per-lane (q = l31)
    float tmx[16];
#pragma unroll
    for (int i = 0; i < 16; ++i) tmx[i] = fmaxf(sc0[i], sc1[i]);
#pragma unroll
    for (int s = 8; s > 0; s >>= 1)
#pragma unroll
      for (int i = 0; i < s; ++i) tmx[i] = fmaxf(tmx[i], tmx[i + s]);
    float mt = tmx[0];
    mt = fmaxf(mt, __shfl_xor(mt, 32));

    // defer-max (T13)
    if (!__all(mt - mrun <= 8.0f)) {
      float mnew = fmaxf(mrun, mt);
      float scl = exp2f(mrun - mnew);
      mrun = mnew;
      lrun *= scl;
#pragma unroll
      for (int d = 0; d < 4; ++d)
#pragma unroll
        for (int j = 0; j < 16; ++j) oacc[d][j] *= scl;
    }

    // P = exp2(S - m) in-register
#pragma unroll
    for (int i = 0; i < 16; ++i) {
      sc0[i] = exp2f(sc0[i] - mrun);
      sc1[i] = exp2f(sc1[i] - mrun);
    }
    float ts[16];
#pragma unroll
    for (int i = 0; i < 16; ++i) ts[i] = sc0[i] + sc1[i];
#pragma unroll
    for (int s = 8; s > 0; s >>= 1)
#pragma unroll
      for (int i = 0; i < s; ++i) ts[i] += ts[i + s];
    float psum = ts[0];
    psum += __shfl_xor(psum, 32);
    lrun += psum;

    // ---- P -> bf16 fragments via cvt_pk + permlane32_swap (T12)
    bf16x8 pa[4];
#pragma unroll
    for (int c = 0; c < 2; ++c) {
      const f32x16& p = c ? sc1 : sc0;
#pragma unroll
      for (int g = 0; g < 2; ++g) {
        const int base = g * 8;
        unsigned a0 = cvtpk_bf16(p[base + 0], p[base + 1]);
        unsigned b0 = cvtpk_bf16(p[base + 4], p[base + 5]);
        pl32swap(a0, b0);
        unsigned a1 = cvtpk_bf16(p[base + 2], p[base + 3]);
        unsigned b1 = cvtpk_bf16(p[base + 6], p[base + 7]);
        pl32swap(a1, b1);
        pa[c * 2 + g] = mk_frag(a0, a1, b0, b1);
      }
    }

    // ---- PV (swapped): oacc[dvb] += mfma(A=Vt rows, B=P^T)
    __builtin_amdgcn_s_setprio(1);
#pragma unroll
    for (int dvb = 0; dvb < 4; ++dvb) {
      int vrow = dvb * 32 + l31;
      int voff = vrow * 128, vswz = (vrow & 7) << 4;
#pragma unroll
      for (int tt = 0; tt < 4; ++tt) {
        bf16x8 vf = ld_frag(ldsV + ((voff + tt * 32 + hi * 16) ^ vswz));
        oacc[dvb] = __builtin_amdgcn_mfma_f32_32x32x16_bf16(vf, pa[tt], oacc[dvb], 0, 0, 0);
      }
    }
    __builtin_amdgcn_s_setprio(0);
    __syncthreads();
  }

  // ---- epilogue: ml + O^T -> O via per-wave LDS transpose, coalesced stores
  if (hi == 0) {
    float* mlp = ml + (size_t)split * 32768 + growq * 2;
    mlp[0] = mrun; mlp[1] = lrun;
  }

  float* po = Po + ((size_t)split << 21) + ((size_t)b * 4096 + qbase) * 128;
  char* tbase = ldsK + wid * 4096;  // 32q x 32dv f32 = 4KB per wave
  for (int dvb = 0; dvb < 4; ++dvb) {
#pragma unroll
    for (int g = 0; g < 4; ++g) {
      float4 w4{oacc[dvb][g * 4 + 0], oacc[dvb][g * 4 + 1],
                oacc[dvb][g * 4 + 2], oacc[dvb][g * 4 + 3]};
      int off = (l31 * 128 + g * 32 + hi * 16) ^ ((l31 & 7) << 4);
      *reinterpret_cast<float4*>(tbase + off) = w4;
    }
    asm volatile("s_waitcnt lgkmcnt(0)" ::: "memory");
    __builtin_amdgcn_sched_barrier(0);
#pragma unroll
    for (int qq = 0; qq < 4; ++qq) {
      int q = qq * 8 + (lane >> 3);
      int off = (q * 128 + (lane & 7) * 16) ^ ((q & 7) << 4);
      float4 r4 = *reinterpret_cast<const float4*>(tbase + off);
      *reinterpret_cast<float4*>(po + (size_t)q * 128 + dvb * 32 + (lane & 7) * 4) = r4;
    }
    asm volatile("s_waitcnt lgkmcnt(0)" ::: "memory");
    __builtin_amdgcn_sched_barrier(0);
  }
}

// ---------------- combine partials ------------------------------------------
template <int NS>
__global__ __launch_bounds__(256) void combine_kernel(const float* __restrict__ Po,
                                                      const float* __restrict__ ml,
                                                      float* __restrict__ out) {
  int idx = blockIdx.x * 256 + threadIdx.x;  // 16384*32 float4-units
  int grow = idx >> 5;
  int c4 = (idx & 31) * 4;
  float m[NS], l[NS];
  float M = -INFINITY;
#pragma unroll
  for (int s = 0; s < NS; ++s) {
    m[s] = ml[(size_t)s * 32768 + grow * 2 + 0];
    l[s] = ml[(size_t)s * 32768 + grow * 2 + 1];
    M = fmaxf(M, m[s]);
  }
  float L = 0.f, w[NS];
#pragma unroll
  for (int s = 0; s < NS; ++s) {
    w[s] = exp2f(m[s] - M);   // log2 domain
    L += l[s] * w[s];
  }
  float invL = 1.0f / L;
  float4 acc = {0.f, 0.f, 0.f, 0.f};
#pragma unroll
  for (int s = 0; s < NS; ++s) {
    float4 p = *reinterpret_cast<const float4*>(Po + ((size_t)s << 21) + (size_t)grow * 128 + c4);
    acc.x += p.x * w[s]; acc.y += p.y * w[s];
    acc.z += p.z * w[s]; acc.w += p.w * w[s];
  }
  acc.x *= invL; acc.y *= invL; acc.z *= invL; acc.w *= invL;
  *reinterpret_cast<float4*>(out + (size_t)grow * 128 + c4) = acc;
}

extern "C" void kernel_launch(void* const* d_in, const int* in_sizes, int n_in,
                              void* d_out, int out_size, void* d_ws, size_t ws_size,
                              hipStream_t stream) {
  const float* q  = (const float*)d_in[0];
  const float* k  = (const float*)d_in[1];
  const float* v  = (const float*)d_in[2];
  const float* Wq = (const float*)d_in[3];
  const float* bq = (const float*)d_in[4];
  const float* Wk = (const float*)d_in[5];
  const float* bk = (const float*)d_in[6];
  const float* Wv = (const float*)d_in[7];
  const float* bv = (const float*)d_in[8];
  float* out = (float*)d_out;

  char* ws = (char*)d_ws;
  unsigned short* Qb  = (unsigned short*)(ws);
  unsigned short* Kb  = (unsigned short*)(ws + (4u << 20));
  unsigned short* Vtb = (unsigned short*)(ws + (8u << 20));
  unsigned short* Wtq = (unsigned short*)(ws + (12u << 20));
  unsigned short* Wtk = (unsigned short*)(ws + (12u << 20) + (256u << 10));
  unsigned short* Wtv = (unsigned short*)(ws + (12u << 20) + (512u << 10));

  const size_t base = (size_t)13 << 20;
  const size_t per = ((size_t)8 << 20) + ((size_t)128 << 10);
  int nsplit = 1;
  if (ws_size >= base + 4 * per) nsplit = 4;
  else if (ws_size >= base + 2 * per) nsplit = 2;
  float* Po = (float*)(ws + base);
  float* ml = (float*)(ws + base + (size_t)nsplit * ((size_t)8 << 20));

  prep_wt_kernel<<<dim3(16, 2, 3), 256, 0, stream>>>(Wq, Wk, Wv, Wtq, Wtk, Wtv);
  proj_kernel<<<dim3(256, 3), 256, 0, stream>>>(q, k, v, Wtq, Wtk, Wtv, bq, bk, bv, Qb, Kb, Vtb);
  attn_kernel<<<dim3(32, nsplit, 4), 256, 0, stream>>>(Qb, Kb, Vtb, Po, ml, 64 / nsplit);
  if (nsplit == 4)      combine_kernel<4><<<2048, 256, 0, stream>>>(Po, ml, out);
  else if (nsplit == 2) combine_kernel<2><<<2048, 256, 0, stream>>>(Po, ml, out);
  else                  combine_kernel<1><<<2048, 256, 0, stream>>>(Po, ml, out);
}